// Round 1
// baseline (3453.406 us; speedup 1.0000x reference)
//
#include <hip/hip_runtime.h>
#include <math.h>

#define SEQ 2048
#define DM  2048
#define NH  8
#define HD  256
#define NB  2

union F4 { float4 v; float f[4]; };

// ---------------- generic NT GEMM: C[m,n] = sum_k A[m,k] * W[n,k] ----------------
// BM=BN=64, BK=16, 256 threads, 4x4 micro-tile per thread.
// MODE 0: C[m*N + n]   MODE 1: q-layout  C[((b*NH+h)*SEQ+s)*HD+d], m=b*SEQ+s, n=h*HD+d
template<int MODE>
__global__ __launch_bounds__(256) void gemm_nt(const float* __restrict__ A,
                                               const float* __restrict__ W,
                                               float* __restrict__ C,
                                               int M, int N, int K)
{
    __shared__ float As[64][20];   // [m][k], padded, float4-aligned
    __shared__ float Bs[16][68];   // [k][n], padded, float4-aligned
    int tid = threadIdx.x;
    int tx = tid & 15, ty = tid >> 4;
    int m0 = blockIdx.y * 64, n0 = blockIdx.x * 64;
    int lm = tid >> 2;            // 0..63
    int lk = (tid & 3) * 4;       // 0,4,8,12
    float acc[4][4] = {};

    for (int k0 = 0; k0 < K; k0 += 16) {
        float4 av = *(const float4*)(A + (size_t)(m0 + lm) * K + k0 + lk);
        float4 bv = *(const float4*)(W + (size_t)(n0 + lm) * K + k0 + lk);
        *(float4*)&As[lm][lk] = av;
        Bs[lk + 0][lm] = bv.x; Bs[lk + 1][lm] = bv.y;
        Bs[lk + 2][lm] = bv.z; Bs[lk + 3][lm] = bv.w;
        __syncthreads();
#pragma unroll
        for (int kk = 0; kk < 16; kk += 4) {
            F4 a4[4], b4[4];
#pragma unroll
            for (int i = 0; i < 4; ++i) a4[i].v = *(const float4*)&As[ty * 4 + i][kk];
#pragma unroll
            for (int u = 0; u < 4; ++u) b4[u].v = *(const float4*)&Bs[kk + u][tx * 4];
#pragma unroll
            for (int i = 0; i < 4; ++i)
#pragma unroll
                for (int j = 0; j < 4; ++j)
                    acc[i][j] += a4[i].f[0] * b4[0].f[j] + a4[i].f[1] * b4[1].f[j]
                               + a4[i].f[2] * b4[2].f[j] + a4[i].f[3] * b4[3].f[j];
        }
        __syncthreads();
    }

#pragma unroll
    for (int i = 0; i < 4; ++i) {
        int m = m0 + ty * 4 + i;
        int n = n0 + tx * 4;
        float4 o = make_float4(acc[i][0], acc[i][1], acc[i][2], acc[i][3]);
        if (MODE == 0) {
            *(float4*)(C + (size_t)m * N + n) = o;
        } else {
            int b = m >> 11, s = m & (SEQ - 1);
            int h = n >> 8, d = n & (HD - 1);
            *(float4*)(C + (((size_t)(b * NH + h)) * SEQ + s) * HD + d) = o;
        }
    }
}

// ---------------- RoPE (in-place on q and k) ----------------
__global__ void rope_kernel(float* __restrict__ q, float* __restrict__ k,
                            const int* __restrict__ pos)
{
    const int QP = NB * NH * SEQ * 128;  // 4,194,304
    const int KP = NB * SEQ * 128;       //   524,288
    const float LN1E4_128 = 0.07195578415606394f;  // ln(10000)/128
    int idx = blockIdx.x * 256 + threadIdx.x;
    if (idx < QP) {
        int d = idx & 127;
        int s = (idx >> 7) & (SEQ - 1);
        int h = (idx >> 18) & (NH - 1);
        int b = idx >> 21;
        float p = (float)pos[b * SEQ + s];
        float fr = p * expf(-(float)d * LN1E4_128);
        float c = cosf(fr), sn = sinf(fr);
        size_t base = (((size_t)(b * NH + h)) * SEQ + s) * HD + d;
        float x0 = q[base], x1 = q[base + 128];
        q[base]       = x0 * c - x1 * sn;
        q[base + 128] = x1 * c + x0 * sn;
    } else {
        int j = idx - QP;
        if (j < KP) {
            int d = j & 127;
            int s = (j >> 7) & (SEQ - 1);
            int b = j >> 18;
            float p = (float)pos[b * SEQ + s];
            float fr = p * expf(-(float)d * LN1E4_128);
            float c = cosf(fr), sn = sinf(fr);
            size_t base = ((size_t)(b * SEQ + s)) * HD + d;
            float x0 = k[base], x1 = k[base + 128];
            k[base]       = x0 * c - x1 * sn;
            k[base + 128] = x1 * c + x0 * sn;
        }
    }
}

// ---------------- pass A: raw scores + online softmax stats ----------------
// block = (64 queries) x one (b,h). Writes RAW (scaled+masked) scores to w_out,
// zero-fills fully-masked tiles, stores per-row running max m and denom l.
__global__ __launch_bounds__(256) void attn_scores(const float* __restrict__ q,
                                                   const float* __restrict__ k,
                                                   const float* __restrict__ mask,
                                                   float* __restrict__ w_out,
                                                   float* __restrict__ m_ws,
                                                   float* __restrict__ l_ws)
{
    __shared__ float As[64][20];
    __shared__ float Bs[16][68];
    __shared__ float red[64][16];
    __shared__ float m_row[64];
    __shared__ float l_row[64];

    int tid = threadIdx.x;
    int tx = tid & 15, ty = tid >> 4;
    int tq = blockIdx.x, h = blockIdx.y, b = blockIdx.z;
    int q0 = tq * 64;
    int lm = tid >> 2, lk = (tid & 3) * 4;

    if (tid < 64) { m_row[tid] = -INFINITY; l_row[tid] = 0.0f; }
    __syncthreads();

    const float* qbase = q + (((size_t)(b * NH + h)) * SEQ + q0) * HD;
    const float* kbase = k + ((size_t)b * SEQ) * HD;
    float* wbase = w_out + (((size_t)(b * NH + h)) * SEQ + q0) * SEQ;

    for (int tk = 0; tk < SEQ / 64; ++tk) {
        if (tk > tq) {
            // fully masked: final weight is exactly 0
            float4 z = make_float4(0.f, 0.f, 0.f, 0.f);
#pragma unroll
            for (int u = 0; u < 4; ++u) {
                int f = u * 1024 + tid * 4;
                int r = f >> 6, c = f & 63;
                *(float4*)(wbase + (size_t)r * SEQ + tk * 64 + c) = z;
            }
            continue;
        }
        float acc[4][4] = {};
        for (int k0 = 0; k0 < HD; k0 += 16) {
            float4 av = *(const float4*)(qbase + (size_t)lm * HD + k0 + lk);
            float4 bv = *(const float4*)(kbase + (size_t)(tk * 64 + lm) * HD + k0 + lk);
            *(float4*)&As[lm][lk] = av;
            Bs[lk + 0][lm] = bv.x; Bs[lk + 1][lm] = bv.y;
            Bs[lk + 2][lm] = bv.z; Bs[lk + 3][lm] = bv.w;
            __syncthreads();
#pragma unroll
            for (int kk = 0; kk < 16; kk += 4) {
                F4 a4[4], b4[4];
#pragma unroll
                for (int i = 0; i < 4; ++i) a4[i].v = *(const float4*)&As[ty * 4 + i][kk];
#pragma unroll
                for (int u = 0; u < 4; ++u) b4[u].v = *(const float4*)&Bs[kk + u][tx * 4];
#pragma unroll
                for (int i = 0; i < 4; ++i)
#pragma unroll
                    for (int j = 0; j < 4; ++j)
                        acc[i][j] += a4[i].f[0] * b4[0].f[j] + a4[i].f[1] * b4[1].f[j]
                                   + a4[i].f[2] * b4[2].f[j] + a4[i].f[3] * b4[3].f[j];
            }
            __syncthreads();
        }
        // scale + mask, write raw scores, per-row partial max
#pragma unroll
        for (int i = 0; i < 4; ++i) {
            int r = ty * 4 + i;
            float4 mk = *(const float4*)(mask + ((size_t)b * SEQ + q0 + r) * SEQ + tk * 64 + tx * 4);
            acc[i][0] = acc[i][0] * 0.0625f + mk.x;
            acc[i][1] = acc[i][1] * 0.0625f + mk.y;
            acc[i][2] = acc[i][2] * 0.0625f + mk.z;
            acc[i][3] = acc[i][3] * 0.0625f + mk.w;
            *(float4*)(wbase + (size_t)r * SEQ + tk * 64 + tx * 4) =
                make_float4(acc[i][0], acc[i][1], acc[i][2], acc[i][3]);
            red[r][tx] = fmaxf(fmaxf(acc[i][0], acc[i][1]), fmaxf(acc[i][2], acc[i][3]));
        }
        __syncthreads();
        if (tid < 64) {
            float mx = m_row[tid];
#pragma unroll
            for (int x = 0; x < 16; ++x) mx = fmaxf(mx, red[tid][x]);
            l_row[tid] *= expf(m_row[tid] - mx);
            m_row[tid] = mx;
        }
        __syncthreads();
#pragma unroll
        for (int i = 0; i < 4; ++i) {
            int r = ty * 4 + i;
            float mn = m_row[r];
            red[r][tx] = expf(acc[i][0] - mn) + expf(acc[i][1] - mn)
                       + expf(acc[i][2] - mn) + expf(acc[i][3] - mn);
        }
        __syncthreads();
        if (tid < 64) {
            float s = 0.f;
#pragma unroll
            for (int x = 0; x < 16; ++x) s += red[tid][x];
            l_row[tid] += s;
        }
        __syncthreads();
    }
    if (tid < 64) {
        size_t off = ((size_t)(b * NH + h)) * SEQ + q0 + tid;
        m_ws[off] = m_row[tid];
        l_ws[off] = l_row[tid];
    }
}

// ---------------- pass B: normalize weights + PV ----------------
__global__ __launch_bounds__(256) void attn_pv(const float* __restrict__ v,
                                               float* __restrict__ w,
                                               const float* __restrict__ m_ws,
                                               const float* __restrict__ l_ws,
                                               float* __restrict__ attn)
{
    __shared__ float w_lds[64][68];
    __shared__ float v_lds[64][68];
    __shared__ float mrow[64];
    __shared__ float linv[64];

    int tid = threadIdx.x, tx = tid & 15, ty = tid >> 4;
    int tq = blockIdx.x, h = blockIdx.y, b = blockIdx.z;
    int q0 = tq * 64;

    if (tid < 64) {
        size_t off = ((size_t)(b * NH + h)) * SEQ + q0 + tid;
        mrow[tid] = m_ws[off];
        linv[tid] = 1.0f / l_ws[off];
    }
    __syncthreads();

    float* wbase = w + (((size_t)(b * NH + h)) * SEQ + q0) * SEQ;
    const float* vbase = v + ((size_t)b * SEQ) * HD;
    float acc[4][4][4] = {};  // [row i][dim chunk][col j]

    for (int tk = 0; tk <= tq; ++tk) {
        // load raw score tile, normalize, write final weights, stash in LDS
#pragma unroll
        for (int u = 0; u < 4; ++u) {
            int f = u * 1024 + tid * 4;
            int r = f >> 6, c = f & 63;
            float4 sv = *(const float4*)(wbase + (size_t)r * SEQ + tk * 64 + c);
            float mn = mrow[r], li = linv[r];
            float4 wv;
            wv.x = expf(sv.x - mn) * li;
            wv.y = expf(sv.y - mn) * li;
            wv.z = expf(sv.z - mn) * li;
            wv.w = expf(sv.w - mn) * li;
            *(float4*)(wbase + (size_t)r * SEQ + tk * 64 + c) = wv;
            *(float4*)&w_lds[r][c] = wv;
        }
        __syncthreads();
#pragma unroll
        for (int ch = 0; ch < 4; ++ch) {
#pragma unroll
            for (int u = 0; u < 4; ++u) {
                int f = u * 1024 + tid * 4;
                int r = f >> 6, c = f & 63;
                *(float4*)&v_lds[r][c] =
                    *(const float4*)(vbase + (size_t)(tk * 64 + r) * HD + ch * 64 + c);
            }
            __syncthreads();
#pragma unroll
            for (int kk = 0; kk < 64; kk += 4) {
                F4 w4[4], v4[4];
#pragma unroll
                for (int i = 0; i < 4; ++i) w4[i].v = *(const float4*)&w_lds[ty * 4 + i][kk];
#pragma unroll
                for (int u = 0; u < 4; ++u) v4[u].v = *(const float4*)&v_lds[kk + u][tx * 4];
#pragma unroll
                for (int i = 0; i < 4; ++i)
#pragma unroll
                    for (int j = 0; j < 4; ++j)
                        acc[i][ch][j] += w4[i].f[0] * v4[0].f[j] + w4[i].f[1] * v4[1].f[j]
                                       + w4[i].f[2] * v4[2].f[j] + w4[i].f[3] * v4[3].f[j];
            }
            __syncthreads();
        }
    }
    // write attn in (b, s, h*HD + d) layout for the final NT GEMM
#pragma unroll
    for (int i = 0; i < 4; ++i)
#pragma unroll
        for (int ch = 0; ch < 4; ++ch) {
            float4 o = make_float4(acc[i][ch][0], acc[i][ch][1], acc[i][ch][2], acc[i][ch][3]);
            *(float4*)(attn + ((size_t)(b * SEQ) + q0 + ty * 4 + i) * DM
                            + h * HD + ch * 64 + tx * 4) = o;
        }
}

extern "C" void kernel_launch(void* const* d_in, const int* in_sizes, int n_in,
                              void* d_out, int out_size, void* d_ws, size_t ws_size,
                              hipStream_t stream)
{
    const float* hs   = (const float*)d_in[0];
    const float* mask = (const float*)d_in[1];
    const int*   pos  = (const int*)d_in[2];
    const float* Wq   = (const float*)d_in[3];
    const float* Wk   = (const float*)d_in[4];
    const float* Wv   = (const float*)d_in[5];
    const float* Wo   = (const float*)d_in[6];

    float* out      = (float*)d_out;
    float* attn_out = out;                                   // B*S*DM
    float* w_out    = out + (size_t)NB * SEQ * DM;           // B*NH*S*S

    float* ws   = (float*)d_ws;
    float* q_ws = ws;                                        // NB*NH*SEQ*HD = 8388608
    float* k_ws = q_ws + (size_t)NB * NH * SEQ * HD;         // NB*SEQ*HD    = 1048576
    float* v_ws = k_ws + (size_t)NB * SEQ * HD;              // NB*SEQ*HD    = 1048576
    float* a_ws = v_ws + (size_t)NB * SEQ * HD;              // NB*SEQ*DM    = 8388608
    float* m_ws = a_ws + (size_t)NB * SEQ * DM;              // NB*NH*SEQ    = 32768
    float* l_ws = m_ws + (size_t)NB * NH * SEQ;              // NB*NH*SEQ    = 32768

    const int M = NB * SEQ;  // 4096

    // projections
    gemm_nt<1><<<dim3(DM / 64, M / 64), 256, 0, stream>>>(hs, Wq, q_ws, M, DM, DM);
    gemm_nt<0><<<dim3(HD / 64, M / 64), 256, 0, stream>>>(hs, Wk, k_ws, M, HD, DM);
    gemm_nt<0><<<dim3(HD / 64, M / 64), 256, 0, stream>>>(hs, Wv, v_ws, M, HD, DM);
    // rope on q and k
    int rope_elems = NB * NH * SEQ * 128 + NB * SEQ * 128;
    rope_kernel<<<(rope_elems + 255) / 256, 256, 0, stream>>>(q_ws, k_ws, pos);
    // attention
    attn_scores<<<dim3(SEQ / 64, NH, NB), 256, 0, stream>>>(q_ws, k_ws, mask, w_out, m_ws, l_ws);
    attn_pv<<<dim3(SEQ / 64, NH, NB), 256, 0, stream>>>(v_ws, w_out, m_ws, l_ws, a_ws);
    // output projection
    gemm_nt<0><<<dim3(DM / 64, M / 64), 256, 0, stream>>>(a_ws, Wo, attn_out, M, DM, DM);
}

// Round 2
// 1191.759 us; speedup vs baseline: 2.8977x; 2.8977x over previous
//
#include <hip/hip_runtime.h>
#include <math.h>

#define SEQ 2048
#define DM  2048
#define NH  8
#define HD  256
#define NB  2

typedef __attribute__((ext_vector_type(8))) short bf16x8;
typedef __attribute__((ext_vector_type(4))) float f32x4;

__device__ inline short f2b(float f) {
    union { float f; unsigned u; } x; x.f = f;
    unsigned r = x.u + 0x7fffu + ((x.u >> 16) & 1u);
    return (short)(r >> 16);
}
__device__ inline float b2f(short s) {
    union { unsigned u; float f; } x;
    x.u = ((unsigned)(unsigned short)s) << 16;
    return x.f;
}

typedef unsigned int u32_g __attribute__((address_space(1)));
typedef unsigned int u32_l __attribute__((address_space(3)));
__device__ inline void gl2lds(const void* g, void* l) {
    __builtin_amdgcn_global_load_lds((const u32_g*)g, (u32_l*)l, 16, 0, 0);
}

// ---------------- fp32 -> bf16 conversion of hs + all weights ----------------
// float4-granular; Wq/Wk/Wv concatenated into wcat [2560][2048].
__global__ void convert_all(const float* __restrict__ hs, const float* __restrict__ wq,
                            const float* __restrict__ wk, const float* __restrict__ wv,
                            const float* __restrict__ wo,
                            short* __restrict__ hsb, short* __restrict__ wcat,
                            short* __restrict__ wob)
{
    int i4 = blockIdx.x * 256 + threadIdx.x;
    const float* src; short* dst; int s4, d4;
    if (i4 < 2097152)      { src = hs; dst = hsb;  s4 = i4;           d4 = s4; }
    else if (i4 < 3145728) { src = wq; dst = wcat; s4 = i4 - 2097152; d4 = s4; }
    else if (i4 < 3276800) { src = wk; dst = wcat; s4 = i4 - 3145728; d4 = 1048576 + s4; }
    else if (i4 < 3407872) { src = wv; dst = wcat; s4 = i4 - 3276800; d4 = 1179648 + s4; }
    else                   { src = wo; dst = wob;  s4 = i4 - 3407872; d4 = s4; }
    float4 v = ((const float4*)src)[s4];
    short4 o;
    o.x = f2b(v.x); o.y = f2b(v.y); o.z = f2b(v.z); o.w = f2b(v.w);
    ((short4*)dst)[d4] = o;
}

// ---------------- bf16 MFMA NT GEMM, 128x128 tile, BK=32 ----------------
// C[m,n] = sum_k A[m,k]*Bw[n,k].  MODE 0: fp32 C[m*N+n].
// MODE 1 (QKV): route col<2048 -> q (b,h,s,d) bf16; col<2304 -> k (b,s,d) bf16;
//               else -> v transposed (b,d,s) bf16.
template<int MODE>
__global__ __launch_bounds__(256, 2) void gemm_bt(const short* __restrict__ A,
                                                  const short* __restrict__ Bw,
                                                  float* __restrict__ C,
                                                  short* __restrict__ q_o,
                                                  short* __restrict__ k_o,
                                                  short* __restrict__ v_o,
                                                  int M, int N, int K)
{
    __shared__ short As[128 * 32];
    __shared__ short Bs[128 * 32];
    int tid = threadIdx.x;
    int lane = tid & 63, w = tid >> 6;
    int lm = lane & 15, quad = lane >> 4;
    int wm = w & 1, wn = w >> 1;
    int m0 = blockIdx.y * 128, n0 = blockIdx.x * 128;

    f32x4 acc[16];
#pragma unroll
    for (int i = 0; i < 16; ++i) acc[i] = (f32x4){0.f, 0.f, 0.f, 0.f};

    const char* Aptr = (const char*)A + (size_t)m0 * K * 2;
    const char* Bptr = (const char*)Bw + (size_t)n0 * K * 2;

    for (int k0 = 0; k0 < K; k0 += 32) {
#pragma unroll
        for (int it = 0; it < 2; ++it) {
            int f = it * 4096 + tid * 16;          // byte offset in 8 KB tile
            int row = f >> 6, colb = f & 63;       // 64 B per row (32 bf16)
            gl2lds(Aptr + (size_t)row * (K * 2) + k0 * 2 + colb, (char*)As + f);
            gl2lds(Bptr + (size_t)row * (K * 2) + k0 * 2 + colb, (char*)Bs + f);
        }
        __syncthreads();
        bf16x8 af[4], bfr[4];
#pragma unroll
        for (int mt = 0; mt < 4; ++mt)
            af[mt] = *(const bf16x8*)(As + (wm * 64 + mt * 16 + lm) * 32 + quad * 8);
#pragma unroll
        for (int nt = 0; nt < 4; ++nt)
            bfr[nt] = *(const bf16x8*)(Bs + (wn * 64 + nt * 16 + lm) * 32 + quad * 8);
#pragma unroll
        for (int mt = 0; mt < 4; ++mt)
#pragma unroll
            for (int nt = 0; nt < 4; ++nt)
                acc[mt * 4 + nt] = __builtin_amdgcn_mfma_f32_16x16x32_bf16(
                    af[mt], bfr[nt], acc[mt * 4 + nt], 0, 0, 0);
        __syncthreads();
    }

#pragma unroll
    for (int mt = 0; mt < 4; ++mt)
#pragma unroll
        for (int nt = 0; nt < 4; ++nt) {
            f32x4 a = acc[mt * 4 + nt];
            int col = n0 + wn * 64 + nt * 16 + lm;
#pragma unroll
            for (int i = 0; i < 4; ++i) {
                int m = m0 + wm * 64 + mt * 16 + quad * 4 + i;
                if (MODE == 0) {
                    C[(size_t)m * N + col] = a[i];
                } else {
                    int b = m >> 11, s = m & (SEQ - 1);
                    short hv = f2b(a[i]);
                    if (col < DM) {
                        int hh = col >> 8, d = col & (HD - 1);
                        q_o[(((size_t)(b * NH + hh)) * SEQ + s) * HD + d] = hv;
                    } else if (col < DM + HD) {
                        int d = col - DM;
                        k_o[((size_t)b * SEQ + s) * HD + d] = hv;
                    } else {
                        int d = col - DM - HD;
                        v_o[((size_t)(b * HD + d)) * SEQ + s] = hv;
                    }
                }
            }
        }
}

// ---------------- RoPE, in-place on bf16 q (b,h,s,d) and k (b,s,d) ----------------
__global__ void rope_kernel(short* __restrict__ q, short* __restrict__ k,
                            const int* __restrict__ pos)
{
    const int QP = NB * NH * SEQ * 128;
    const int KP = NB * SEQ * 128;
    const float C0 = 0.07195578415606394f;  // ln(10000)/128
    int idx = blockIdx.x * 256 + threadIdx.x;
    if (idx < QP) {
        int d = idx & 127;
        int s = (idx >> 7) & (SEQ - 1);
        int h = (idx >> 18) & (NH - 1);
        int b = idx >> 21;
        float p = (float)pos[b * SEQ + s];
        float fr = p * expf(-(float)d * C0);
        float c = cosf(fr), sn = sinf(fr);
        size_t base = (((size_t)(b * NH + h)) * SEQ + s) * HD + d;
        float x0 = b2f(q[base]), x1 = b2f(q[base + 128]);
        q[base]       = f2b(x0 * c - x1 * sn);
        q[base + 128] = f2b(x1 * c + x0 * sn);
    } else {
        int j = idx - QP;
        if (j < KP) {
            int d = j & 127;
            int s = (j >> 7) & (SEQ - 1);
            int b = j >> 18;
            float p = (float)pos[b * SEQ + s];
            float fr = p * expf(-(float)d * C0);
            float c = cosf(fr), sn = sinf(fr);
            size_t base = ((size_t)(b * SEQ + s)) * HD + d;
            float x0 = b2f(k[base]), x1 = b2f(k[base + 128]);
            k[base]       = f2b(x0 * c - x1 * sn);
            k[base + 128] = f2b(x1 * c + x0 * sn);
        }
    }
}

// ---------------- fused flash attention + weights output ----------------
// grid (32, NH, NB); tq = 31 - blockIdx.x (LPT: big blocks first).
// Block = 4 independent waves; wave w owns 16 query rows. No __syncthreads.
__device__ inline void qk_tile(const short* __restrict__ kbase, const bf16x8* qf,
                               int lm, int quad, f32x4 sa[4])
{
#pragma unroll
    for (int nt = 0; nt < 4; ++nt) sa[nt] = (f32x4){0.f, 0.f, 0.f, 0.f};
#pragma unroll
    for (int ks = 0; ks < 8; ++ks) {
#pragma unroll
        for (int nt = 0; nt < 4; ++nt) {
            bf16x8 kf = *(const bf16x8*)(kbase + (size_t)(nt * 16 + lm) * HD + ks * 32 + quad * 8);
            sa[nt] = __builtin_amdgcn_mfma_f32_16x16x32_bf16(qf[ks], kf, sa[nt], 0, 0, 0);
        }
    }
}

__global__ __launch_bounds__(256, 2) void attn_fused(const short* __restrict__ qb,
                                                     const short* __restrict__ kb,
                                                     const short* __restrict__ vT,
                                                     float* __restrict__ w_out,
                                                     short* __restrict__ a_o)
{
    __shared__ short P[4][16][72];   // per-wave P tile, padded (+8) to break banks
    int tid = threadIdx.x;
    int w = tid >> 6, lane = tid & 63;
    int lm = lane & 15, quad = lane >> 4;
    int tq = 31 - blockIdx.x;
    int h = blockIdx.y, b = blockIdx.z;
    int q0 = tq * 64;
    int r0 = q0 + w * 16;

    const short* qrow = qb + (((size_t)(b * NH + h)) * SEQ + r0 + lm) * HD;
    bf16x8 qf[8];
#pragma unroll
    for (int ks = 0; ks < 8; ++ks)
        qf[ks] = *(const bf16x8*)(qrow + ks * 32 + quad * 8);

    float m_r[4], l_r[4];
    f32x4 O[16];
#pragma unroll
    for (int i = 0; i < 4; ++i) { m_r[i] = -INFINITY; l_r[i] = 0.f; }
#pragma unroll
    for (int i = 0; i < 16; ++i) O[i] = (f32x4){0.f, 0.f, 0.f, 0.f};

    const short* kb0 = kb + (size_t)b * SEQ * HD;
    const short* vb0 = vT + (size_t)b * HD * SEQ;

    for (int tk = 0; tk <= tq; ++tk) {
        f32x4 sa[4];
        qk_tile(kb0 + (size_t)tk * 64 * HD, qf, lm, quad, sa);

        float vals[4][4];
#pragma unroll
        for (int nt = 0; nt < 4; ++nt)
#pragma unroll
            for (int i = 0; i < 4; ++i) {
                float v = sa[nt][i] * 0.0625f;
                if (tk == tq && (nt * 16 + lm) > (w * 16 + quad * 4 + i)) v -= 1e9f;
                vals[nt][i] = v;
            }
        float mnew[4], alpha[4], ps[4];
#pragma unroll
        for (int i = 0; i < 4; ++i) {
            float mx = fmaxf(fmaxf(vals[0][i], vals[1][i]), fmaxf(vals[2][i], vals[3][i]));
            mx = fmaxf(mx, __shfl_xor(mx, 1));
            mx = fmaxf(mx, __shfl_xor(mx, 2));
            mx = fmaxf(mx, __shfl_xor(mx, 4));
            mx = fmaxf(mx, __shfl_xor(mx, 8));
            mnew[i] = fmaxf(m_r[i], mx);
            alpha[i] = expf(m_r[i] - mnew[i]);
            ps[i] = 0.f;
        }
#pragma unroll
        for (int nt = 0; nt < 4; ++nt)
#pragma unroll
            for (int i = 0; i < 4; ++i) {
                float p = expf(vals[nt][i] - mnew[i]);
                ps[i] += p;
                P[w][quad * 4 + i][nt * 16 + lm] = f2b(p);
            }
        f32x4 al;
#pragma unroll
        for (int i = 0; i < 4; ++i) {
            float t = ps[i];
            t += __shfl_xor(t, 1); t += __shfl_xor(t, 2);
            t += __shfl_xor(t, 4); t += __shfl_xor(t, 8);
            l_r[i] = l_r[i] * alpha[i] + t;
            m_r[i] = mnew[i];
            al[i] = alpha[i];
        }
#pragma unroll
        for (int nt2 = 0; nt2 < 16; ++nt2) O[nt2] *= al;

        const short* prow = &P[w][lm][0];
#pragma unroll
        for (int kc = 0; kc < 2; ++kc) {
            bf16x8 pf = *(const bf16x8*)(prow + kc * 32 + quad * 8);
            const short* vbase = vb0 + tk * 64 + kc * 32 + quad * 8;
#pragma unroll
            for (int nt2 = 0; nt2 < 16; ++nt2) {
                bf16x8 vf = *(const bf16x8*)(vbase + (size_t)(nt2 * 16 + lm) * SEQ);
                O[nt2] = __builtin_amdgcn_mfma_f32_16x16x32_bf16(pf, vf, O[nt2], 0, 0, 0);
            }
        }
    }

    f32x4 li;
#pragma unroll
    for (int i = 0; i < 4; ++i) li[i] = 1.f / l_r[i];

    // store O (bf16, (b, s, h*HD+d) layout for the Wo GEMM)
#pragma unroll
    for (int nt2 = 0; nt2 < 16; ++nt2)
#pragma unroll
        for (int i = 0; i < 4; ++i) {
            size_t s = (size_t)q0 + w * 16 + quad * 4 + i;
            a_o[((size_t)b * SEQ + s) * DM + h * HD + nt2 * 16 + lm] = f2b(O[nt2][i] * li[i]);
        }

    // pass 2: recompute scores, write normalized attention weights (fp32)
    float* wb = w_out + (((size_t)(b * NH + h)) * SEQ) * SEQ;
    for (int tk = 0; tk <= tq; ++tk) {
        f32x4 sa[4];
        qk_tile(kb0 + (size_t)tk * 64 * HD, qf, lm, quad, sa);
#pragma unroll
        for (int nt = 0; nt < 4; ++nt)
#pragma unroll
            for (int i = 0; i < 4; ++i) {
                float v = sa[nt][i] * 0.0625f;
                if (tk == tq && (nt * 16 + lm) > (w * 16 + quad * 4 + i)) v -= 1e9f;
                float wv = expf(v - m_r[i]) * li[i];
                wb[(size_t)(r0 + quad * 4 + i) * SEQ + tk * 64 + nt * 16 + lm] = wv;
            }
    }

    // zero-fill the fully-masked upper-triangle tiles (block-cooperative)
    int zs = (tq + 1) * 64;
    if (zs < SEQ) {
        int r = tid >> 2, c0 = (tid & 3) * 4;
        float* wr = wb + (size_t)(q0 + r) * SEQ;
        float4 z = make_float4(0.f, 0.f, 0.f, 0.f);
        for (int c = zs + c0; c < SEQ; c += 16)
            *(float4*)(wr + c) = z;
    }
}

extern "C" void kernel_launch(void* const* d_in, const int* in_sizes, int n_in,
                              void* d_out, int out_size, void* d_ws, size_t ws_size,
                              hipStream_t stream)
{
    const float* hs   = (const float*)d_in[0];
    const int*   pos  = (const int*)d_in[2];
    const float* Wq   = (const float*)d_in[3];
    const float* Wk   = (const float*)d_in[4];
    const float* Wv   = (const float*)d_in[5];
    const float* Wo   = (const float*)d_in[6];

    float* out      = (float*)d_out;
    float* attn_out = out;                           // B*S*DM fp32
    float* w_out    = out + (size_t)NB * SEQ * DM;   // B*NH*S*S fp32

    // workspace (bf16 shorts), total 56.6 MB
    short* hsb  = (short*)d_ws;            // 8,388,608  (hs bf16; aliased as attn out a_b after QKV GEMM)
    short* a_b  = hsb;                     // alias: hsb dead once QKV GEMM has run
    short* wcat = hsb + 8388608;           // 5,242,880  (Wq|Wk|Wv bf16, [2560][2048])
    short* wob  = wcat + 5242880;          // 4,194,304  (Wo bf16)
    short* qx   = wob + 4194304;           // 8,388,608  (q bf16 (b,h,s,d), rope in-place)
    short* kx   = qx + 8388608;            // 1,048,576  (k bf16 (b,s,d), rope in-place)
    short* vTx  = kx + 1048576;            // 1,048,576  (v bf16 transposed (b,d,s))

    convert_all<<<17408, 256, 0, stream>>>(hs, Wq, Wk, Wv, Wo, hsb, wcat, wob);
    gemm_bt<1><<<dim3(20, 32), 256, 0, stream>>>(hsb, wcat, nullptr, qx, kx, vTx,
                                                 NB * SEQ, DM + 2 * HD, DM);
    rope_kernel<<<18432, 256, 0, stream>>>(qx, kx, pos);
    attn_fused<<<dim3(32, NH, NB), 256, 0, stream>>>(qx, kx, vTx, w_out, a_b);
    gemm_bt<0><<<dim3(16, 32), 256, 0, stream>>>(a_b, wob, attn_out, nullptr, nullptr, nullptr,
                                                 NB * SEQ, DM, DM);
}

// Round 3
// 648.944 us; speedup vs baseline: 5.3216x; 1.8365x over previous
//
#include <hip/hip_runtime.h>
#include <math.h>

#define SEQ 2048
#define DM  2048
#define NH  8
#define HD  256
#define NB  2

typedef __attribute__((ext_vector_type(8))) short bf16x8;
typedef __attribute__((ext_vector_type(4))) float f32x4;

__device__ inline short f2b(float f) {
    union { float f; unsigned u; } x; x.f = f;
    unsigned r = x.u + 0x7fffu + ((x.u >> 16) & 1u);
    return (short)(r >> 16);
}
__device__ inline float b2f(short s) {
    union { unsigned u; float f; } x;
    x.u = ((unsigned)(unsigned short)s) << 16;
    return x.f;
}

typedef unsigned int u32_g __attribute__((address_space(1)));
typedef unsigned int u32_l __attribute__((address_space(3)));
__device__ inline void gl2lds(const void* g, void* l) {
    __builtin_amdgcn_global_load_lds((const u32_g*)g, (u32_l*)l, 16, 0, 0);
}

// ---------------- fp32 -> bf16 conversion of hs + all weights ----------------
__global__ void convert_all(const float* __restrict__ hs, const float* __restrict__ wq,
                            const float* __restrict__ wk, const float* __restrict__ wv,
                            const float* __restrict__ wo,
                            short* __restrict__ hsb, short* __restrict__ wcat,
                            short* __restrict__ wob)
{
    int i4 = blockIdx.x * 256 + threadIdx.x;
    const float* src; short* dst; int s4, d4;
    if (i4 < 2097152)      { src = hs; dst = hsb;  s4 = i4;           d4 = s4; }
    else if (i4 < 3145728) { src = wq; dst = wcat; s4 = i4 - 2097152; d4 = s4; }
    else if (i4 < 3276800) { src = wk; dst = wcat; s4 = i4 - 3145728; d4 = 1048576 + s4; }
    else if (i4 < 3407872) { src = wv; dst = wcat; s4 = i4 - 3276800; d4 = 1179648 + s4; }
    else                   { src = wo; dst = wob;  s4 = i4 - 3407872; d4 = s4; }
    float4 v = ((const float4*)src)[s4];
    short4 o;
    o.x = f2b(v.x); o.y = f2b(v.y); o.z = f2b(v.z); o.w = f2b(v.w);
    ((short4*)dst)[d4] = o;
}

// ---------------- bf16 MFMA NT GEMM, 128x128 tile, BK=32 ----------------
// MODE 0: fp32 C[m*N+n].
// MODE 1 (QKV): col<2048 -> q (b,h,s,d); col<2304 -> k (b,s,d) CHUNK-SWIZZLED by s&31;
//               else -> v transposed (b,d,s) with s-chunk (within 64) swizzled by d&7.
template<int MODE>
__global__ __launch_bounds__(256, 2) void gemm_bt(const short* __restrict__ A,
                                                  const short* __restrict__ Bw,
                                                  float* __restrict__ C,
                                                  short* __restrict__ q_o,
                                                  short* __restrict__ k_o,
                                                  short* __restrict__ v_o,
                                                  int M, int N, int K)
{
    __shared__ short As[128 * 32];
    __shared__ short Bs[128 * 32];
    int tid = threadIdx.x;
    int lane = tid & 63, w = tid >> 6;
    int lm = lane & 15, quad = lane >> 4;
    int wm = w & 1, wn = w >> 1;
    int m0 = blockIdx.y * 128, n0 = blockIdx.x * 128;

    f32x4 acc[16];
#pragma unroll
    for (int i = 0; i < 16; ++i) acc[i] = (f32x4){0.f, 0.f, 0.f, 0.f};

    const char* Aptr = (const char*)A + (size_t)m0 * K * 2;
    const char* Bptr = (const char*)Bw + (size_t)n0 * K * 2;

    for (int k0 = 0; k0 < K; k0 += 32) {
#pragma unroll
        for (int it = 0; it < 2; ++it) {
            int f = it * 4096 + tid * 16;
            int row = f >> 6, colb = f & 63;
            gl2lds(Aptr + (size_t)row * (K * 2) + k0 * 2 + colb, (char*)As + f);
            gl2lds(Bptr + (size_t)row * (K * 2) + k0 * 2 + colb, (char*)Bs + f);
        }
        __syncthreads();
        bf16x8 af[4], bfr[4];
#pragma unroll
        for (int mt = 0; mt < 4; ++mt)
            af[mt] = *(const bf16x8*)(As + (wm * 64 + mt * 16 + lm) * 32 + quad * 8);
#pragma unroll
        for (int nt = 0; nt < 4; ++nt)
            bfr[nt] = *(const bf16x8*)(Bs + (wn * 64 + nt * 16 + lm) * 32 + quad * 8);
#pragma unroll
        for (int mt = 0; mt < 4; ++mt)
#pragma unroll
            for (int nt = 0; nt < 4; ++nt)
                acc[mt * 4 + nt] = __builtin_amdgcn_mfma_f32_16x16x32_bf16(
                    af[mt], bfr[nt], acc[mt * 4 + nt], 0, 0, 0);
        __syncthreads();
    }

#pragma unroll
    for (int mt = 0; mt < 4; ++mt)
#pragma unroll
        for (int nt = 0; nt < 4; ++nt) {
            f32x4 a = acc[mt * 4 + nt];
            int col = n0 + wn * 64 + nt * 16 + lm;
#pragma unroll
            for (int i = 0; i < 4; ++i) {
                int m = m0 + wm * 64 + mt * 16 + quad * 4 + i;
                if (MODE == 0) {
                    C[(size_t)m * N + col] = a[i];
                } else {
                    int b = m >> 11, s = m & (SEQ - 1);
                    short hv = f2b(a[i]);
                    if (col < DM) {
                        int hh = col >> 8, d = col & (HD - 1);
                        q_o[(((size_t)(b * NH + hh)) * SEQ + s) * HD + d] = hv;
                    } else if (col < DM + HD) {
                        int d = col - DM;
                        int c2 = (d >> 3) ^ (s & 31);
                        k_o[((size_t)b * SEQ + s) * HD + (c2 << 3) + (d & 7)] = hv;
                    } else {
                        int d = col - DM - HD;
                        int sc = ((s >> 3) & 7) ^ (d & 7);
                        v_o[((size_t)(b * HD + d)) * SEQ + (s & ~63) + (sc << 3) + (s & 7)] = hv;
                    }
                }
            }
        }
}

// ---------------- RoPE: q (b,h,s,d) plain; k (b,s,d) chunk-swizzled ----------------
__global__ void rope_kernel(short* __restrict__ q, short* __restrict__ k,
                            const int* __restrict__ pos)
{
    const int QP = NB * NH * SEQ * 128;
    const int KP = NB * SEQ * 128;
    const float C0 = 0.07195578415606394f;  // ln(10000)/128
    int idx = blockIdx.x * 256 + threadIdx.x;
    if (idx < QP) {
        int d = idx & 127;
        int s = (idx >> 7) & (SEQ - 1);
        int h = (idx >> 18) & (NH - 1);
        int b = idx >> 21;
        float p = (float)pos[b * SEQ + s];
        float fr = p * expf(-(float)d * C0);
        float c = cosf(fr), sn = sinf(fr);
        size_t base = (((size_t)(b * NH + h)) * SEQ + s) * HD + d;
        float x0 = b2f(q[base]), x1 = b2f(q[base + 128]);
        q[base]       = f2b(x0 * c - x1 * sn);
        q[base + 128] = f2b(x1 * c + x0 * sn);
    } else {
        int j = idx - QP;
        if (j < KP) {
            int d = j & 127;              // actual d in [0,128)
            int s = (j >> 7) & (SEQ - 1);
            int b = j >> 18;
            float p = (float)pos[b * SEQ + s];
            float fr = p * expf(-(float)d * C0);
            float c = cosf(fr), sn = sinf(fr);
            // swizzled positions: e0 for d, e0^128 for d+128
            int e0 = ((((d >> 3) ^ (s & 31)) & 31) << 3) | (d & 7);
            size_t base = ((size_t)(b * SEQ + s)) * HD;
            float x0 = b2f(k[base + e0]), x1 = b2f(k[base + (e0 ^ 128)]);
            k[base + e0]         = f2b(x0 * c - x1 * sn);
            k[base + (e0 ^ 128)] = f2b(x1 * c + x0 * sn);
        }
    }
}

// ---------------- fused flash attention + weights output ----------------
// 1-D grid of 512 blocks, globally LPT-ordered: tq = 31 - idx/16, (h,b) = idx%16.
// 4 waves/block; wave w owns 16 query rows; K/V tiles staged in LDS cooperatively.
__global__ __launch_bounds__(256, 2) void attn_flash(const short* __restrict__ qb,
                                                     const short* __restrict__ kb,
                                                     const short* __restrict__ vT,
                                                     float* __restrict__ w_out,
                                                     short* __restrict__ a_o)
{
    __shared__ short Ks[64 * 256];    // [s_l][256], chunks swizzled by s&31
    __shared__ short Vs[256 * 64];    // [d][64],   chunks swizzled by d&7
    __shared__ short P[4][16][72];

    int tid = threadIdx.x;
    int w = tid >> 6, lane = tid & 63;
    int lm = lane & 15, quad = lane >> 4;
    int idx = blockIdx.x;
    int hb = idx & 15;
    int h = hb & 7, b = hb >> 3;
    int tq = 31 - (idx >> 4);
    int q0 = tq * 64;
    int r0 = q0 + w * 16;

    const short* qrow = qb + (((size_t)(b * NH + h)) * SEQ + r0 + lm) * HD;
    bf16x8 qf[8];
#pragma unroll
    for (int ks = 0; ks < 8; ++ks)
        qf[ks] = *(const bf16x8*)(qrow + ks * 32 + quad * 8);

    float m_r[4], l_r[4];
    f32x4 O[16];
#pragma unroll
    for (int i = 0; i < 4; ++i) { m_r[i] = -INFINITY; l_r[i] = 0.f; }
#pragma unroll
    for (int i = 0; i < 16; ++i) O[i] = (f32x4){0.f, 0.f, 0.f, 0.f};

    const short* kb0 = kb + (size_t)b * SEQ * HD;
    const short* vb0 = vT + (size_t)b * HD * SEQ;

    for (int tk = 0; tk <= tq; ++tk) {
        // ---- stage K (32 KB) + V (32 KB), linear LDS, coalesced global ----
        const char* kt = (const char*)(kb0 + (size_t)tk * 64 * HD);
#pragma unroll
        for (int it = 0; it < 8; ++it) {
            int g = it * 256 + tid;
            gl2lds(kt + ((size_t)(g >> 5) * HD + (g & 31) * 8) * 2, (char*)Ks + g * 16);
            gl2lds((const char*)vb0 + ((size_t)(g >> 3) * SEQ + tk * 64 + (g & 7) * 8) * 2,
                   (char*)Vs + g * 16);
        }
        __syncthreads();

        // ---- QK from LDS ----
        f32x4 sa[4];
#pragma unroll
        for (int nt = 0; nt < 4; ++nt) sa[nt] = (f32x4){0.f, 0.f, 0.f, 0.f};
#pragma unroll
        for (int ks = 0; ks < 8; ++ks)
#pragma unroll
            for (int nt = 0; nt < 4; ++nt) {
                int s_l = nt * 16 + lm;
                bf16x8 kf = *(const bf16x8*)(Ks + s_l * 256 +
                                             (((ks * 4 + quad) ^ (s_l & 31)) << 3));
                sa[nt] = __builtin_amdgcn_mfma_f32_16x16x32_bf16(qf[ks], kf, sa[nt], 0, 0, 0);
            }

        float vals[4][4];
#pragma unroll
        for (int nt = 0; nt < 4; ++nt)
#pragma unroll
            for (int i = 0; i < 4; ++i) {
                float v = sa[nt][i] * 0.0625f;
                if (tk == tq && (nt * 16 + lm) > (w * 16 + quad * 4 + i)) v -= 1e9f;
                vals[nt][i] = v;
            }
        float mnew[4], alpha[4], ps[4];
#pragma unroll
        for (int i = 0; i < 4; ++i) {
            float mx = fmaxf(fmaxf(vals[0][i], vals[1][i]), fmaxf(vals[2][i], vals[3][i]));
            mx = fmaxf(mx, __shfl_xor(mx, 1));
            mx = fmaxf(mx, __shfl_xor(mx, 2));
            mx = fmaxf(mx, __shfl_xor(mx, 4));
            mx = fmaxf(mx, __shfl_xor(mx, 8));
            mnew[i] = fmaxf(m_r[i], mx);
            alpha[i] = expf(m_r[i] - mnew[i]);
            ps[i] = 0.f;
        }
#pragma unroll
        for (int nt = 0; nt < 4; ++nt)
#pragma unroll
            for (int i = 0; i < 4; ++i) {
                float p = expf(vals[nt][i] - mnew[i]);
                ps[i] += p;
                P[w][quad * 4 + i][nt * 16 + lm] = f2b(p);
            }
        f32x4 al;
#pragma unroll
        for (int i = 0; i < 4; ++i) {
            float t = ps[i];
            t += __shfl_xor(t, 1); t += __shfl_xor(t, 2);
            t += __shfl_xor(t, 4); t += __shfl_xor(t, 8);
            l_r[i] = l_r[i] * alpha[i] + t;
            m_r[i] = mnew[i];
            al[i] = alpha[i];
        }
#pragma unroll
        for (int nt2 = 0; nt2 < 16; ++nt2) O[nt2] *= al;

        // ---- PV from LDS ----
        const short* prow = &P[w][lm][0];
#pragma unroll
        for (int kc = 0; kc < 2; ++kc) {
            bf16x8 pf = *(const bf16x8*)(prow + kc * 32 + quad * 8);
#pragma unroll
            for (int nt2 = 0; nt2 < 16; ++nt2) {
                int d_l = nt2 * 16 + lm;
                bf16x8 vf = *(const bf16x8*)(Vs + d_l * 64 +
                                             (((kc * 4 + quad) ^ (d_l & 7)) << 3));
                O[nt2] = __builtin_amdgcn_mfma_f32_16x16x32_bf16(pf, vf, O[nt2], 0, 0, 0);
            }
        }
        __syncthreads();
    }

    f32x4 li;
#pragma unroll
    for (int i = 0; i < 4; ++i) li[i] = 1.f / l_r[i];

    // store O (bf16, (b, s, h*HD+d) layout for the Wo GEMM)
#pragma unroll
    for (int nt2 = 0; nt2 < 16; ++nt2)
#pragma unroll
        for (int i = 0; i < 4; ++i) {
            size_t s = (size_t)q0 + w * 16 + quad * 4 + i;
            a_o[((size_t)b * SEQ + s) * DM + h * HD + nt2 * 16 + lm] = f2b(O[nt2][i] * li[i]);
        }

    // ---- pass 2: recompute scores from LDS-staged K, write normalized weights ----
    float* wb = w_out + (((size_t)(b * NH + h)) * SEQ) * SEQ;
    for (int tk = 0; tk <= tq; ++tk) {
        const char* kt = (const char*)(kb0 + (size_t)tk * 64 * HD);
#pragma unroll
        for (int it = 0; it < 8; ++it) {
            int g = it * 256 + tid;
            gl2lds(kt + ((size_t)(g >> 5) * HD + (g & 31) * 8) * 2, (char*)Ks + g * 16);
        }
        __syncthreads();
        f32x4 sa[4];
#pragma unroll
        for (int nt = 0; nt < 4; ++nt) sa[nt] = (f32x4){0.f, 0.f, 0.f, 0.f};
#pragma unroll
        for (int ks = 0; ks < 8; ++ks)
#pragma unroll
            for (int nt = 0; nt < 4; ++nt) {
                int s_l = nt * 16 + lm;
                bf16x8 kf = *(const bf16x8*)(Ks + s_l * 256 +
                                             (((ks * 4 + quad) ^ (s_l & 31)) << 3));
                sa[nt] = __builtin_amdgcn_mfma_f32_16x16x32_bf16(qf[ks], kf, sa[nt], 0, 0, 0);
            }
#pragma unroll
        for (int nt = 0; nt < 4; ++nt)
#pragma unroll
            for (int i = 0; i < 4; ++i) {
                float v = sa[nt][i] * 0.0625f;
                if (tk == tq && (nt * 16 + lm) > (w * 16 + quad * 4 + i)) v -= 1e9f;
                float wv = expf(v - m_r[i]) * li[i];
                wb[(size_t)(r0 + quad * 4 + i) * SEQ + tk * 64 + nt * 16 + lm] = wv;
            }
        __syncthreads();
    }

    // zero-fill the fully-masked upper-triangle tiles (block-cooperative)
    int zs = (tq + 1) * 64;
    if (zs < SEQ) {
        int r = tid >> 2, c0 = (tid & 3) * 4;
        float* wr = wb + (size_t)(q0 + r) * SEQ;
        float4 z = make_float4(0.f, 0.f, 0.f, 0.f);
        for (int c = zs + c0; c < SEQ; c += 16)
            *(float4*)(wr + c) = z;
    }
}

extern "C" void kernel_launch(void* const* d_in, const int* in_sizes, int n_in,
                              void* d_out, int out_size, void* d_ws, size_t ws_size,
                              hipStream_t stream)
{
    const float* hs   = (const float*)d_in[0];
    const int*   pos  = (const int*)d_in[2];
    const float* Wq   = (const float*)d_in[3];
    const float* Wk   = (const float*)d_in[4];
    const float* Wv   = (const float*)d_in[5];
    const float* Wo   = (const float*)d_in[6];

    float* out      = (float*)d_out;
    float* attn_out = out;                           // B*S*DM fp32
    float* w_out    = out + (size_t)NB * SEQ * DM;   // B*NH*S*S fp32

    short* hsb  = (short*)d_ws;            // hs bf16; aliased as attn out a_b after QKV GEMM
    short* a_b  = hsb;
    short* wcat = hsb + 8388608;           // Wq|Wk|Wv bf16 [2560][2048]
    short* wob  = wcat + 5242880;          // Wo bf16
    short* qx   = wob + 4194304;           // q bf16 (b,h,s,d)
    short* kx   = qx + 8388608;            // k bf16 (b,s,d) chunk-swizzled
    short* vTx  = kx + 1048576;            // v bf16 (b,d,s) chunk-swizzled

    convert_all<<<17408, 256, 0, stream>>>(hs, Wq, Wk, Wv, Wo, hsb, wcat, wob);
    gemm_bt<1><<<dim3(20, 32), 256, 0, stream>>>(hsb, wcat, nullptr, qx, kx, vTx,
                                                 NB * SEQ, DM + 2 * HD, DM);
    rope_kernel<<<18432, 256, 0, stream>>>(qx, kx, pos);
    attn_flash<<<512, 256, 0, stream>>>(qx, kx, vTx, w_out, a_b);
    gemm_bt<0><<<dim3(16, 32), 256, 0, stream>>>(a_b, wob, attn_out, nullptr, nullptr, nullptr,
                                                 NB * SEQ, DM, DM);
}